// Round 5
// baseline (421.072 us; speedup 1.0000x reference)
//
#include <hip/hip_runtime.h>
#include <hip/hip_bf16.h>

#define NT   8
#define INF  128
#define OUTF 64
#define BR   128    // rows per chunk

typedef __attribute__((ext_vector_type(8))) short short8;   // 8 bf16 (4 VGPRs)
typedef __attribute__((ext_vector_type(4))) float f32x4;

__device__ __forceinline__ short f2bf(float f) {
  __hip_bfloat16 h = __float2bfloat16(f);
  return __builtin_bit_cast(short, h);
}

// ---------------------------------------------------------------------------
// wbf[128 * 512] shorts (128 KB) in d_ws: W as bf16 in MFMA B-fragment order.
//   frag fi = (t*4 + s)*4 + nb, lane(q,c), j:
//   wbf[fi*512 + lane*8 + j] = bf16( W[t][s*32 + q*8 + j][nb*16 + c] )
// (verified in earlier rounds)
// ---------------------------------------------------------------------------
__global__ void hl_wconv(const float* __restrict__ W, short* __restrict__ wbf) {
  const int tid   = blockIdx.x * blockDim.x + threadIdx.x;  // 0..8191
  const int combo = tid >> 6;                               // 0..127 == fi
  const int lane  = tid & 63;
  const int t = combo >> 4, s = (combo >> 2) & 3, nb = combo & 3;
  const int q = lane >> 4, c = lane & 15;
  const float* Wt = W + t * INF * OUTF;
  short8 v;
  #pragma unroll
  for (int j = 0; j < 8; ++j)
    v[j] = f2bf(Wt[(s * 32 + q * 8 + j) * OUTF + nb * 16 + c]);
  *(short8*)(wbf + (size_t)tid * 8) = v;
}

// ---------------------------------------------------------------------------
// Persistent double-buffered pipeline, 1 block/CU (129 KB LDS), 512 threads.
// Grid-stride over 128-row chunks. Per iteration:
//   A) issue global_load_lds DMA for chunk k+1 into buf^1 (64 KB, no VGPRs)
//      + rank atomics for k+1's binning (overlaps DMA shadow)
//   B) compute chunk k from buf: one MFMA tile per (type,16-row group);
//      B-frags from L2-hot wbf; A-frags = LDS f32 (XOR-swizzled) -> cvt bf16
//   C) barrier (compiler drains DMA+stores); close binning (lorder/descs);
//      recycle lcnt; barrier.
// gload_lds writes LDS linearly -> swizzle achieved by pre-swizzling the
// per-lane GLOBAL source address with ^((row&15)<<4); the read side applies
// the same XOR (involution, both-sides rule).
// Fragment mappings (verified in prior rounds):
//   A: m = lane&15, k = q*8 + j ;  B: k = s*32+q*8+j, n = nb*16+c
//   C/D: n(col) = lane&15 in-col c, m(row) = q*4 + reg
// ---------------------------------------------------------------------------
__global__ __launch_bounds__(512, 2) void hl_pp(
    const float* __restrict__ x, const int* __restrict__ nty,
    const short* __restrict__ wbf, const float* __restrict__ b,
    float* __restrict__ out, int N) {
  __shared__ float xs[2][BR * INF];       // 2 x 64 KB, swizzled f32
  __shared__ int   lcnt[2][NT];
  __shared__ short lorder[2][BR];
  __shared__ int   descs[2][16];          // t | valid<<3 | loff<<8  (<=15 used)
  __shared__ int   ndesc[2];

  const int tid  = threadIdx.x;           // 0..511
  const int wave = tid >> 6, lane = tid & 63;
  const int q = lane >> 4, c = lane & 15;
  const int nchunks = (N + BR - 1) / BR;
  const int ck0 = blockIdx.x;
  const short* wp = wbf + lane * 8;       // + fi*512 per fragment
  if (ck0 >= nchunks) return;             // block-uniform

  // DMA one 64-KB chunk: 8 instrs/wave, instr j covers rows 2*(wave*8+j)..+1
  auto STAGE = [&](int ck, int bb) {
    const int base = ck * BR;
    const int nr = min(BR, N - base);
    #pragma unroll
    for (int j = 0; j < 8; ++j) {
      const int pr = (wave * 8 + j) * 2;
      const int r  = pr + (lane >> 5);            // dest row in chunk
      const int rc = (r < nr) ? r : (nr - 1);     // tail clamp (source valid)
      const int sb = ((lane & 31) * 16) ^ ((r & 15) << 4);  // pre-swz source
      const char* src = (const char*)(x + (size_t)(base + rc) * INF) + sb;
      __builtin_amdgcn_global_load_lds(
          (const __attribute__((address_space(1))) void*)src,
          (__attribute__((address_space(3))) void*)(&xs[bb][0] + (size_t)(wave * 8 + j) * 256),
          16, 0, 0);
    }
  };

  // ---- prologue: stage + bin chunk ck0 into slot 0 ----
  if (tid < 2 * NT) ((int*)lcnt)[tid] = 0;
  STAGE(ck0, 0);
  const int base0 = ck0 * BR;
  const int nr0 = min(BR, N - base0);
  int ty0 = 0;
  if (tid < nr0) ty0 = nty[base0 + tid];
  __syncthreads();                        // lcnt zeroed
  int rk0 = 0;
  if (tid < nr0) rk0 = atomicAdd(&lcnt[0][ty0], 1);
  __syncthreads();                        // counts final
  if (tid < nr0) {
    int cb = 0;
    #pragma unroll
    for (int t = 0; t < NT; ++t) cb += (t < ty0) ? lcnt[0][t] : 0;
    lorder[0][cb + rk0] = (short)tid;
  }
  if (tid == 0) {
    int nd = 0, o2 = 0;
    for (int t = 0; t < NT; ++t) {
      const int cn = lcnt[0][t];
      for (int j2 = 0; j2 < cn; j2 += 16)
        descs[0][nd++] = t | (min(16, cn - j2) << 3) | ((o2 + j2) << 8);
      o2 += cn;
    }
    ndesc[0] = nd;
  }
  __syncthreads();                        // lorder/descs visible; DMA0 drained

  // ---- main loop ----
  int cur = 0;
  for (int ck = ck0; ck < nchunks; ck += gridDim.x, cur ^= 1) {
    const int nxt = ck + gridDim.x;
    const int o = cur ^ 1;
    const bool hasnxt = (nxt < nchunks);  // block-uniform

    // A) issue next DMA + rank (lcnt[o] was zeroed before last barrier)
    int tyn = 0, rkn = 0, nrn = 0;
    if (hasnxt) {
      STAGE(nxt, o);
      const int bn = nxt * BR;
      nrn = min(BR, N - bn);
      if (tid < nrn) {
        tyn = nty[bn + tid];
        rkn = atomicAdd(&lcnt[o][tyn], 1);
      }
    }

    // B) compute chunk ck from xs[cur]
    const int base = ck * BR;
    const int nd = ndesc[cur];
    for (int i = wave; i < nd; i += 8) {
      const int d = descs[cur][i];
      const int t = d & 7, valid = (d >> 3) & 31, loff = d >> 8;

      short8 B[4][4];                     // 16 x 16B L2 loads, issued upfront
      #pragma unroll
      for (int s = 0; s < 4; ++s)
        #pragma unroll
        for (int nb = 0; nb < 4; ++nb)
          B[s][nb] = *(const short8*)(wp + (size_t)((t * 4 + s) * 4 + nb) * 512);

      const int am = c < valid ? c : valid - 1;   // dup last row for pad lanes
      const int lr = lorder[cur][loff + am];
      const char* xrow = (const char*)&xs[cur][lr * INF];
      const int sw = (lr & 15) << 4;

      f32x4 av[8];                        // all 8 ds_reads issued upfront
      #pragma unroll
      for (int s = 0; s < 4; ++s) {
        av[s * 2]     = *(const f32x4*)(xrow + ((s * 128 + q * 32) ^ sw));
        av[s * 2 + 1] = *(const f32x4*)(xrow + ((s * 128 + q * 32 + 16) ^ sw));
      }

      f32x4 acc[4];
      #pragma unroll
      for (int nb = 0; nb < 4; ++nb) acc[nb] = (f32x4){0, 0, 0, 0};
      #pragma unroll
      for (int s = 0; s < 4; ++s) {
        short8 a;
        #pragma unroll
        for (int j2 = 0; j2 < 4; ++j2) {
          a[j2]     = f2bf(av[s * 2][j2]);
          a[j2 + 4] = f2bf(av[s * 2 + 1][j2]);
        }
        #pragma unroll
        for (int nb = 0; nb < 4; ++nb)
          acc[nb] = __builtin_amdgcn_mfma_f32_16x16x32_bf16(a, B[s][nb], acc[nb], 0, 0, 0);
      }

      float bv[4];
      #pragma unroll
      for (int nb = 0; nb < 4; ++nb) bv[nb] = b[t * OUTF + nb * 16 + c];
      #pragma unroll
      for (int r = 0; r < 4; ++r) {
        const int m = q * 4 + r;
        if (m < valid) {
          const int grow = base + lorder[cur][loff + m];
          float* orow = out + (size_t)grow * OUTF + c;
          #pragma unroll
          for (int nb = 0; nb < 4; ++nb)
            orow[nb * 16] = acc[nb][r] + bv[nb];
        }
      }
    }

    // C) close binning of next; recycle lcnt[cur]
    __syncthreads();                      // ranks done; compute done; DMA drained
    if (hasnxt) {
      if (tid < nrn) {
        int cb = 0;
        #pragma unroll
        for (int t = 0; t < NT; ++t) cb += (t < tyn) ? lcnt[o][t] : 0;
        lorder[o][cb + rkn] = (short)tid;
      }
      if (tid == 0) {
        int nd2 = 0, o2 = 0;
        for (int t = 0; t < NT; ++t) {
          const int cn = lcnt[o][t];
          for (int j2 = 0; j2 < cn; j2 += 16)
            descs[o][nd2++] = t | (min(16, cn - j2) << 3) | ((o2 + j2) << 8);
          o2 += cn;
        }
        ndesc[o] = nd2;
      }
    }
    if (tid < NT) lcnt[cur][tid] = 0;     // ready for chunk after next
    __syncthreads();
  }
}

extern "C" void kernel_launch(void* const* d_in, const int* in_sizes, int n_in,
                              void* d_out, int out_size, void* d_ws, size_t ws_size,
                              hipStream_t stream) {
  const float* x  = (const float*)d_in[0];
  const int*   nt = (const int*)d_in[1];
  const float* W  = (const float*)d_in[2];
  const float* b  = (const float*)d_in[3];
  float* out = (float*)d_out;
  const int N = in_sizes[1];
  short* wbf = (short*)d_ws;              // 128 KB (ws >= 128 KB, proven)

  hl_wconv<<<32, 256, 0, stream>>>(W, wbf);
  const int nchunks = (N + BR - 1) / BR;
  const int gb = nchunks < 256 ? nchunks : 256;
  hl_pp<<<gb, 512, 0, stream>>>(x, nt, wbf, b, out, N);
}